// Round 4
// baseline (506.410 us; speedup 1.0000x reference)
//
#include <hip/hip_runtime.h>
#include <stdint.h>

#define D_MODEL 1024
#define N_HEADS 16
#define D_HEAD  64
#define BATCH   4
#define SEQ     4096
#define BS      (BATCH*SEQ)     // 16384
#define QKV_N   (3*D_MODEL)     // 3072
#define HB      (N_HEADS*BATCH) // 64
#define NCHUNK  8
#define CH_S    (SEQ/NCHUNK)    // 512

using f16x8 = __attribute__((ext_vector_type(8))) _Float16;
using f32x4 = __attribute__((ext_vector_type(4))) float;
using i32x4 = __attribute__((ext_vector_type(4))) int;
typedef __attribute__((address_space(3))) ushort AS3U;

__device__ static inline ushort f2h(float f) {
    _Float16 h = (_Float16)f; ushort u; __builtin_memcpy(&u, &h, 2); return u;
}
__device__ static inline void async16(const ushort* g, ushort* l) {
    __builtin_amdgcn_global_load_lds(
        (const __attribute__((address_space(1))) void*)g,
        (__attribute__((address_space(3))) void*)l, 16, 0, 0);
}

// ---------------- K0: fp32 -> fp16 for x and W in one launch ----------------
__global__ __launch_bounds__(256)
void cvt_both(const float* __restrict__ x, const float* __restrict__ W,
              ushort* __restrict__ xh, ushort* __restrict__ Wh, int nx)
{
    int i = (blockIdx.x * 256 + threadIdx.x) * 8;
    const float* src; ushort* dst; int o;
    if (i < nx) { src = x; dst = xh; o = i; }
    else        { src = W; dst = Wh; o = i - nx; }
    float4 a = *(const float4*)(src + o);
    float4 b = *(const float4*)(src + o + 4);
    *(ushort4*)(dst + o)     = make_ushort4(f2h(a.x),f2h(a.y),f2h(a.z),f2h(a.w));
    *(ushort4*)(dst + o + 4) = make_ushort4(f2h(b.x),f2h(b.y),f2h(b.z),f2h(b.w));
}

// ---------------- K1: 256x256-tile 8-phase pipelined fp16 MFMA GEMM ----------------
// Geometry: BM=BN=256, BK=64, 8 waves 2Mx4N, 128KB LDS, 8x16KB chunks,
// st-swizzle via pre-swizzled global source (rule #21).
// ROUND-4 FIX: pin waves_per_eu to (2,2). LDS=128KB already caps the CU at
// 1 block (2 waves/SIMD); round 2/3's allocator targeted the 128-VGPR cliff
// (4 waves/EU) anyway and spilled ~60 regs/thread to scratch -> ~300 MB of
// extra HBM write traffic per launch (WRITE_SIZE 415 MB vs 101 ideal) and
// every phase stalled on scratch. Pinning gives the 256-reg budget the
// ~200-reg demand (acc 128 + frags 32 + addr ~40) actually needs: no spill.
// Wait ledger unchanged from round 3 (vmcnt(8) at even phases; stage FIFO
// p1:ch5 p2:ch7 p3:ch0 p4:ch2 p5:ch1 p6:ch3 p7:ch4 p8:ch6; every chunk
// retired 4-5 phases after stage-issue; prologue ch0,2,1,3,4,6 + vmcnt(8);
// tail VM8/VM4/VM0). Fragment reads are inline-asm ds_read_b128 so no
// compiler-inserted per-phase vmcnt(0) drains; explicit lgkmcnt(0) +
// sched_barrier(0) before MFMAs per rule #18.
#define MF(a,b,c) __builtin_amdgcn_mfma_f32_16x16x32_f16(a,b,c,0,0,0)
#define FENCE asm volatile("" ::: "memory")
#define VM8 asm volatile("s_waitcnt vmcnt(8)" ::: "memory")
#define VM4 asm volatile("s_waitcnt vmcnt(4)" ::: "memory")
#define VM0 asm volatile("s_waitcnt vmcnt(0)" ::: "memory")
#define VMN do {} while (0)
#define NOSTAGE do {} while (0)

#define STAGE(CH, S0, S1, KC) do { \
    async16((S0) + (KC), &lds[(CH)*8192 + d0]); \
    async16((S1) + (KC), &lds[(CH)*8192 + d1]); } while (0)

// asm ds_read_b128: P is an AS3 ushort*, IMM is a byte offset (<65536)
#define DSR(D, P, IMM) do { i32x4 _t; \
    asm volatile("ds_read_b128 %0, %1 offset:%2" : "=v"(_t) : "v"(P), "n"(IMM)); \
    D = __builtin_bit_cast(f16x8, _t); } while (0)

#define MROW(AI, I) \
    acc[(I)*4+0]=MF(AI,b0,acc[(I)*4+0]); \
    acc[(I)*4+1]=MF(AI,b1,acc[(I)*4+1]); \
    acc[(I)*4+2]=MF(AI,b2,acc[(I)*4+2]); \
    acc[(I)*4+3]=MF(AI,b3,acc[(I)*4+3]);

#define MROWS(AI, I) \
    acc[(I)*4+0]=MF(b0,AI,acc[(I)*4+0]); \
    acc[(I)*4+1]=MF(b1,AI,acc[(I)*4+1]); \
    acc[(I)*4+2]=MF(b2,AI,acc[(I)*4+2]); \
    acc[(I)*4+3]=MF(b3,AI,acc[(I)*4+3]);

#define PHASE(CA, CB, IH, STG, VMW) do { \
    const AS3U* pa = lA + (CA)*8192; \
    const AS3U* pb = lB + (CB)*8192; \
    f16x8 a0,a1,a2,a3,b0,b1,b2,b3; \
    DSR(a0, pa, ((IH)*4+0)*1024); \
    DSR(a1, pa, ((IH)*4+1)*1024); \
    DSR(a2, pa, ((IH)*4+2)*1024); \
    DSR(a3, pa, ((IH)*4+3)*1024); \
    DSR(b0, pb, 0*1024); \
    DSR(b1, pb, 1*1024); \
    DSR(b2, pb, 2*1024); \
    DSR(b3, pb, 3*1024); \
    STG; \
    FENCE; __builtin_amdgcn_s_barrier(); \
    asm volatile("s_waitcnt lgkmcnt(0)" ::: "memory"); \
    __builtin_amdgcn_sched_barrier(0); \
    __builtin_amdgcn_s_setprio(1); \
    if (!isV) { \
        MROW(a0,(IH)*4+0) MROW(a1,(IH)*4+1) MROW(a2,(IH)*4+2) MROW(a3,(IH)*4+3) \
    } else { \
        MROWS(a0,(IH)*4+0) MROWS(a1,(IH)*4+1) MROWS(a2,(IH)*4+2) MROWS(a3,(IH)*4+3) \
    } \
    __builtin_amdgcn_s_setprio(0); \
    VMW; \
    FENCE; __builtin_amdgcn_s_barrier(); FENCE; \
  } while (0)

__global__ __launch_bounds__(512)
__attribute__((amdgpu_waves_per_eu(2, 2)))
void qkv_gemm_f16(const ushort* __restrict__ Ah, const ushort* __restrict__ Bh,
                  const float* __restrict__ bias,
                  ushort* __restrict__ qh, ushort* __restrict__ kh,
                  ushort* __restrict__ varr)
{
    __shared__ ushort lds[8 * 8192];   // 128 KB
    const int t = threadIdx.x;
    const int lane = t & 63, w = t >> 6;

    // XCD-aware bijective block swizzle (768 blocks, 768%8==0)
    const int id0 = blockIdx.y * 12 + blockIdx.x;
    const int ids = (id0 & 7) * 96 + (id0 >> 3);
    const int n0 = (ids % 12) * 256;
    const int m0 = (ids / 12) * 256;

    const int wm = (w >> 2) * 128;     // wave's M offset (2 waves in M)
    const int wn = (w & 3) * 64;       // wave's N offset (4 waves in N)
    const int fr = lane & 15;
    const int hq = lane >> 4;

    // staging: source pre-swizzled so LDS dests stay linear (rule #21)
    const int u0 = t, u1 = 512 + t;
    const int rp0 = u0 >> 3, rp1 = u1 >> 3;
    const int sl0 = (u0 & 7) ^ (rp0 & 7), sl1 = (u1 & 7) ^ (rp1 & 7);
    const int r0 = rp0 * 2 + (sl0 >> 2), r1 = rp1 * 2 + (sl1 >> 2);
    const int c0 = (sl0 & 3) * 8,        c1 = (sl1 & 3) * 8;
    const ushort* aS0 = Ah + (size_t)(m0 + r0) * D_MODEL + c0;
    const ushort* aS1 = Ah + (size_t)(m0 + r1) * D_MODEL + c1;
    const ushort* bS0 = Bh + (size_t)(n0 + r0) * D_MODEL + c0;
    const ushort* bS1 = Bh + (size_t)(n0 + r1) * D_MODEL + c1;
    const int d0 = w * 512;            // wave-uniform LDS slice, load 0
    const int d1 = 4096 + w * 512;     // load 1

    // fragment-read offset (lane-constant): row = base + fr, k-slot = hq
    const int rdo  = ((fr >> 1) * 64) + ((((fr & 1) * 4 + hq) ^ ((fr >> 1) & 7)) * 8);
    const AS3U* lA = (const AS3U*)lds + (wm * 32 + rdo);
    const AS3U* lB = (const AS3U*)lds + (wn * 32 + rdo);

    const int cgb = n0 + wn;                    // 64-aligned output-column base
    const int typ = __builtin_amdgcn_readfirstlane((cgb % 192) / 64); // 0=q,1=k,2=v
    const bool isV = (typ == 2);

    f32x4 acc[32] = {};   // q/k: acc[i*4+j] = D[s i][ci j]; v: transposed

    // ---- prologue: kt0 (4 chunks) + kt1 k0 (2 chunks); vmcnt(8) -> ch0,ch2 ready
    STAGE(0, aS0, aS1, 0);
    STAGE(2, bS0, bS1, 0);
    STAGE(1, aS0, aS1, 32);
    STAGE(3, bS0, bS1, 32);
    STAGE(4, aS0, aS1, 64);
    STAGE(6, bS0, bS1, 64);
    VM8;
    __builtin_amdgcn_s_barrier();
    FENCE;

    #pragma unroll 1
    for (int it = 0; it < 7; ++it) {
        const int kb = it * 128;
        PHASE(0,2,0, STAGE(5, aS0,aS1, kb+96),  VMN);
        PHASE(0,2,1, STAGE(7, bS0,bS1, kb+96),  VM8);
        PHASE(1,3,0, STAGE(0, aS0,aS1, kb+128), VMN);
        PHASE(1,3,1, STAGE(2, bS0,bS1, kb+128), VM8);
        PHASE(4,6,0, STAGE(1, aS0,aS1, kb+160), VMN);
        PHASE(4,6,1, STAGE(3, bS0,bS1, kb+160), VM8);
        PHASE(5,7,0, STAGE(4, aS0,aS1, kb+192), VMN);
        PHASE(5,7,1, STAGE(6, bS0,bS1, kb+192), VM8);
    }
    // ---- tail iteration (kt14, kt15): only kt15's k1 chunks still to stage ----
    PHASE(0,2,0, STAGE(5, aS0,aS1, 992), VMN);
    PHASE(0,2,1, STAGE(7, bS0,bS1, 992), VM8);
    PHASE(1,3,0, NOSTAGE, VMN);
    PHASE(1,3,1, NOSTAGE, VM4);
    PHASE(4,6,0, NOSTAGE, VMN);
    PHASE(4,6,1, NOSTAGE, VM0);
    PHASE(5,7,0, NOSTAGE, VMN);
    PHASE(5,7,1, NOSTAGE, VMN);

    // ---- epilogue: C/D row=(lane>>4)*4+r, col=lane&15 (validated) ----
    const int col = lane & 15, rq = (lane >> 4) * 4;
    const int h   = cgb / 192;
    const int b   = m0 >> 12;
    const int sbl = (m0 & 4095) + wm;

    if (typ < 2) {
        ushort* dst = typ ? kh : qh;
        #pragma unroll
        for (int j = 0; j < 4; ++j) {
            const int ci = j*16 + col;
            const float bj = bias[cgb + ci];
            const size_t rowoff = ((size_t)(h*4 + b)*64 + ci) * SEQ;
            #pragma unroll
            for (int i = 0; i < 8; ++i) {
                const int s0 = sbl + i*16 + rq;            // multiple of 4
                float v0 = acc[i*4+j][0] + bj, v1 = acc[i*4+j][1] + bj;
                float v2 = acc[i*4+j][2] + bj, v3 = acc[i*4+j][3] + bj;
                if (s0 < 32) {
                    // RoPE via inline fast-math intrinsics (no lib calls):
                    // angle = ci * 10000^(-mp/16) = ci * exp(-mp*ln(10000)/16)
                    int mp = s0 >> 1;
                    float if0 = __expf(-0.5756462732485115f * (float)mp);
                    float if1 = __expf(-0.5756462732485115f * (float)(mp + 1));
                    float a0 = (float)ci * if0, a1 = (float)ci * if1;
                    float cc0 = __cosf(a0), s0n = __sinf(a0);
                    float cc1 = __cosf(a1), s1n = __sinf(a1);
                    float n0_ = v0*cc0 - v1*s0n, n1_ = v1*cc0 + v0*s0n;
                    float n2_ = v2*cc1 - v3*s1n, n3_ = v3*cc1 + v2*s1n;
                    v0 = n0_; v1 = n1_; v2 = n2_; v3 = n3_;
                }
                *(ushort4*)&dst[rowoff + s0] = make_ushort4(
                    f2h(v0), f2h(v1), f2h(v2), f2h(v3));
            }
        }
    } else {
        // swapped-operand acc: acc[i*4+j][r] is at ci = j*16+rq+r, s = sbl+i*16+col
        const size_t base = (size_t)(h*4 + b) * SEQ;
        #pragma unroll
        for (int j = 0; j < 4; ++j) {
            const float4 b4 = *(const float4*)&bias[cgb + j*16 + rq];
            #pragma unroll
            for (int i = 0; i < 8; ++i) {
                const int s = sbl + i*16 + col;
                *(ushort4*)&varr[(base + s)*64 + j*16 + rq] = make_ushort4(
                    f2h(acc[i*4+j][0] + b4.x), f2h(acc[i*4+j][1] + b4.y),
                    f2h(acc[i*4+j][2] + b4.z), f2h(acc[i*4+j][3] + b4.w));
            }
        }
    }
}

// ---------------- K2: partial scores (MFMA) per K-chunk ----------------
__global__ __launch_bounds__(256)
void scores_partial(const ushort* __restrict__ qh, const ushort* __restrict__ kh,
                    float* __restrict__ partial)
{
    __shared__ float L[4 * 4096];   // 64 KB: per-wave 64x64 partials
    const int t = threadIdx.x, lane = t & 63, w = t >> 6;
    const int hb = blockIdx.x, chunk = blockIdx.y;
    const ushort* qb = qh + (size_t)hb * 64 * SEQ;
    const ushort* kb = kh + (size_t)hb * 64 * SEQ;
    const int fr = lane & 15, fq = (lane >> 4) * 8;

    f32x4 acc[4][4] = {};
    const int kbase = chunk * CH_S + w * (CH_S / 4);
    for (int kk = 0; kk < CH_S / 4; kk += 32) {
        const int k0 = kbase + kk;
        f16x8 af[4], bf[4];
        #pragma unroll
        for (int i = 0; i < 4; ++i)
            af[i] = *(const f16x8*)&qb[(size_t)(i*16 + fr) * SEQ + k0 + fq];
        #pragma unroll
        for (int j = 0; j < 4; ++j)
            bf[j] = *(const f16x8*)&kb[(size_t)(j*16 + fr) * SEQ + k0 + fq];
        #pragma unroll
        for (int i = 0; i < 4; ++i)
            #pragma unroll
            for (int j = 0; j < 4; ++j)
                acc[i][j] = __builtin_amdgcn_mfma_f32_16x16x32_f16(
                                af[i], bf[j], acc[i][j], 0, 0, 0);
    }

    float* Lw = &L[w * 4096];
    const int col = lane & 15, rq = (lane >> 4) * 4;
    #pragma unroll
    for (int i = 0; i < 4; ++i)
        #pragma unroll
        for (int j = 0; j < 4; ++j)
            #pragma unroll
            for (int r = 0; r < 4; ++r)
                Lw[(i*16 + rq + r)*64 + j*16 + col] = acc[i][j][r];
    __syncthreads();

    float* pb = partial + ((size_t)hb * NCHUNK + chunk) * 4096;
    #pragma unroll
    for (int u = 0; u < 4; ++u) {
        int idx = u*1024 + t*4;
        f32x4 s = *(f32x4*)&L[idx];
        s += *(f32x4*)&L[4096 + idx];
        s += *(f32x4*)&L[8192 + idx];
        s += *(f32x4*)&L[12288 + idx];
        *(f32x4*)&pb[idx] = s;
    }
}

// ---------------- K3: sum chunks, softmax over e; P fp16 [d][e] ----------------
__global__ __launch_bounds__(256)
void softmax_k(const float* __restrict__ partial, ushort* __restrict__ Pt)
{
    __shared__ float L[64 * 65];   // padded: row d at L[d*65]
    const int t = threadIdx.x;
    const int hb = blockIdx.x;
    const float* pb = partial + (size_t)hb * NCHUNK * 4096;

    #pragma unroll
    for (int u = 0; u < 16; ++u) {
        int idx = u*256 + t;              // coalesced global reads
        float s = 0.f;
        #pragma unroll
        for (int c = 0; c < NCHUNK; ++c) s += pb[c*4096 + idx];
        L[(idx >> 6) * 65 + (idx & 63)] = s;
    }
    __syncthreads();

    if (t < 64) {
        float* row = &L[t * 65];          // stride 65: conflict-free across lanes
        float mx = -1e30f;
        for (int e = 0; e < 64; ++e) mx = fmaxf(mx, row[e]);
        float sum = 0.f;
        for (int e = 0; e < 64; ++e) {
            float v = expf(0.125f * (row[e] - mx));
            row[e] = v; sum += v;
        }
        float inv = 1.f / sum;
        ushort* pd = Pt + (size_t)hb * 4096 + t * 64;
        for (int e = 0; e < 64; ++e) pd[e] = f2h(row[e] * inv);
    }
}

// ---------------- K4: out^T[s][d] = sum_e v[s][e] * P[d][e]  (MFMA, K=64) ----------------
__global__ __launch_bounds__(256)
void attn_out_mfma(const ushort* __restrict__ varr, const ushort* __restrict__ Pt,
                   float* __restrict__ out)
{
    const int t = threadIdx.x, lane = t & 63, w = t >> 6;
    const int hb = blockIdx.x;
    const int sb = blockIdx.y * 256 + w * 64;
    const int fr = lane & 15, fq = (lane >> 4) * 8;

    const ushort* Pb = Pt + (size_t)hb * 4096;
    const ushort* vb = varr + (size_t)hb * SEQ * 64;

    f16x8 aV[4][2], bP[4][2];
    #pragma unroll
    for (int i = 0; i < 4; ++i)
        #pragma unroll
        for (int ks = 0; ks < 2; ++ks)
            aV[i][ks] = *(const f16x8*)&vb[(size_t)(sb + i*16 + fr)*64 + ks*32 + fq];
    #pragma unroll
    for (int j = 0; j < 4; ++j)
        #pragma unroll
        for (int ks = 0; ks < 2; ++ks)
            bP[j][ks] = *(const f16x8*)&Pb[(j*16 + fr)*64 + ks*32 + fq];

    f32x4 acc[4][4] = {};   // [s-tile][d-tile]
    #pragma unroll
    for (int ks = 0; ks < 2; ++ks)
        #pragma unroll
        for (int i = 0; i < 4; ++i)
            #pragma unroll
            for (int j = 0; j < 4; ++j)
                acc[i][j] = __builtin_amdgcn_mfma_f32_16x16x32_f16(
                                aV[i][ks], bP[j][ks], acc[i][j], 0, 0, 0);

    const int col = lane & 15, rq = (lane >> 4) * 4;
    const int h = hb >> 2, b = hb & 3;
    #pragma unroll
    for (int i = 0; i < 4; ++i)
        #pragma unroll
        for (int j = 0; j < 4; ++j) {
            const int dg = j*16 + col;
            size_t off = (((size_t)h*64 + dg)*4 + b)*SEQ + sb + i*16 + rq;
            *(float4*)&out[off] = make_float4(acc[i][j][0], acc[i][j][1],
                                              acc[i][j][2], acc[i][j][3]);
        }
}

// ---------------- launcher ----------------
extern "C" void kernel_launch(void* const* d_in, const int* in_sizes, int n_in,
                              void* d_out, int out_size, void* d_ws, size_t ws_size,
                              hipStream_t stream)
{
    const float* x    = (const float*)d_in[0];
    const float* W    = (const float*)d_in[1];
    const float* bias = (const float*)d_in[2];
    float* out = (float*)d_out;

    char* p = (char*)d_ws;
    ushort* qh   = (ushort*)p;  p += (size_t)HB * 64 * SEQ * 2;        // 33.6 MB
    ushort* kh   = (ushort*)p;  p += (size_t)HB * 64 * SEQ * 2;        // 33.6 MB
    ushort* varr = (ushort*)p;  p += (size_t)HB * SEQ * 64 * 2;        // 33.6 MB
    ushort* Pth  = (ushort*)p;  p += (size_t)HB * 4096 * 2;            //  0.5 MB
    float* partial = (float*)p; p += (size_t)HB * NCHUNK * 4096 * 4;   //  8.4 MB
    ushort* xh   = (ushort*)p;  p += (size_t)BS * D_MODEL * 2;         // 33.6 MB
    ushort* Wh   = (ushort*)p;  p += (size_t)QKV_N * D_MODEL * 2;      //  6.3 MB

    const int nx = BS * D_MODEL;       // 16777216
    const int nw = QKV_N * D_MODEL;    // 3145728
    cvt_both<<<(nx + nw)/2048, 256, 0, stream>>>(x, W, xh, Wh, nx);

    qkv_gemm_f16<<<dim3(QKV_N/256, BS/256), 512, 0, stream>>>(
        xh, Wh, bias, qh, kh, varr);

    scores_partial<<<dim3(HB, NCHUNK), 256, 0, stream>>>(qh, kh, partial);
    softmax_k<<<HB, 256, 0, stream>>>(partial, Pth);
    attn_out_mfma<<<dim3(HB, 16), 256, 0, stream>>>(varr, Pth, out);
}

// Round 5
// 315.614 us; speedup vs baseline: 1.6045x; 1.6045x over previous
//
#include <hip/hip_runtime.h>
#include <stdint.h>

#define D_MODEL 1024
#define N_HEADS 16
#define D_HEAD  64
#define BATCH   4
#define SEQ     4096
#define BS      (BATCH*SEQ)     // 16384
#define QKV_N   (3*D_MODEL)     // 3072
#define HB      (N_HEADS*BATCH) // 64
#define NCHUNK  8
#define CH_S    (SEQ/NCHUNK)    // 512

using f16x8 = __attribute__((ext_vector_type(8))) _Float16;
using f32x4 = __attribute__((ext_vector_type(4))) float;
using i32x4 = __attribute__((ext_vector_type(4))) int;
typedef __attribute__((address_space(3))) ushort AS3U;

__device__ static inline ushort f2h(float f) {
    _Float16 h = (_Float16)f; ushort u; __builtin_memcpy(&u, &h, 2); return u;
}
__device__ static inline void async16(const ushort* g, ushort* l) {
    __builtin_amdgcn_global_load_lds(
        (const __attribute__((address_space(1))) void*)g,
        (__attribute__((address_space(3))) void*)l, 16, 0, 0);
}

// ---------------- K0: fp32 -> fp16 for x and W in one launch ----------------
__global__ __launch_bounds__(256)
void cvt_both(const float* __restrict__ x, const float* __restrict__ W,
              ushort* __restrict__ xh, ushort* __restrict__ Wh, int nx)
{
    int i = (blockIdx.x * 256 + threadIdx.x) * 8;
    const float* src; ushort* dst; int o;
    if (i < nx) { src = x; dst = xh; o = i; }
    else        { src = W; dst = Wh; o = i - nx; }
    float4 a = *(const float4*)(src + o);
    float4 b = *(const float4*)(src + o + 4);
    *(ushort4*)(dst + o)     = make_ushort4(f2h(a.x),f2h(a.y),f2h(a.z),f2h(a.w));
    *(ushort4*)(dst + o + 4) = make_ushort4(f2h(b.x),f2h(b.y),f2h(b.z),f2h(b.w));
}

// ---------------- K1: 128x128-tile double-buffered fp16 MFMA GEMM ----------------
// ROUND-5: revert to the PROVEN round-0 geometry (BM=BN=128, BK=32, 256 thr,
// 4 waves 2Mx2N, acc[4][4] = 64 VGPR -> total ~115, fits the 128 budget: no
// spill, unlike the 256^2 structure which pinned at 128 VGPR and spilled
// ~300 MB/launch in rounds 2-4). On top of round 0, apply only the three
// individually-verified deltas:
//  1. Conflict-free LDS swizzle (r2-r4: SQ_LDS_BANK_CONFLICT == 0). Chunk =
//     [64 row-pairs][8 slots of 16B]; phys_slot = ((r&1)*4+k4) ^ ((r>>1)&7);
//     global source pre-swizzled so global_load_lds dests stay linear.
//     (Round 0 paid 1.26e7 conflicts = 8-way on stride-64B fragment reads.)
//  2. T3-minimum 2-phase pipeline: one barrier per K-step.
//        step: STAGE(next buf); ds_read cur; lgkmcnt(0); MFMA x16;
//              vmcnt(0); s_barrier.
//     Safety: each wave drains lgkmcnt before MFMAs, so at the end-of-step
//     barrier all reads of cur are complete -> next step may overwrite cur;
//     vmcnt(0) before the barrier -> next buf is fully landed. Stage latency
//     hides under the 16 MFMAs + ~4 blocks/CU TLP (round 0 exposed it fully:
//     stage/barrier/compute/barrier).
//  3. XCD-aware bijective block swizzle (3072 blocks, 3072%8==0).
// Fragment reads are inline-asm ds_read_b128 (invisible to alias analysis ->
// no compiler-inserted per-step vmcnt(0) between STAGE and ds_read; rule #18:
// explicit lgkmcnt(0)+sched_barrier(0) before MFMAs). v-type waves compute
// mfma(B,A) (transposed D) so v stores are ushort4 (proven r2-r4).
#define MF(a,b,c) __builtin_amdgcn_mfma_f32_16x16x32_f16(a,b,c,0,0,0)
#define FENCE asm volatile("" ::: "memory")
#define VM0 asm volatile("s_waitcnt vmcnt(0)" ::: "memory")

// asm ds_read_b128: P is an AS3 ushort*, IMM is a byte offset (<65536)
#define DSR(D, P, IMM) do { i32x4 _t; \
    asm volatile("ds_read_b128 %0, %1 offset:%2" : "=v"(_t) : "v"(P), "n"(IMM)); \
    D = __builtin_bit_cast(f16x8, _t); } while (0)

// stage both operands' next chunk (4 x global_load_lds_dwordx4 per thread)
#define STAGE_AB(NXT, KT) do { \
    async16(aS0 + (KT)*32, &lds[(NXT)*4096 + d0]); \
    async16(aS1 + (KT)*32, &lds[(NXT)*4096 + d1]); \
    async16(bS0 + (KT)*32, &lds[8192 + (NXT)*4096 + d0]); \
    async16(bS1 + (KT)*32, &lds[8192 + (NXT)*4096 + d1]); } while (0)

#define STEP(CUR, STG) do { \
    STG; \
    const AS3U* pa = lA + (CUR)*4096; \
    const AS3U* pb = lB + (CUR)*4096; \
    f16x8 a0,a1,a2,a3,b0,b1,b2,b3; \
    DSR(a0, pa, 0); DSR(a1, pa, 1024); DSR(a2, pa, 2048); DSR(a3, pa, 3072); \
    DSR(b0, pb, 0); DSR(b1, pb, 1024); DSR(b2, pb, 2048); DSR(b3, pb, 3072); \
    asm volatile("s_waitcnt lgkmcnt(0)" ::: "memory"); \
    __builtin_amdgcn_sched_barrier(0); \
    __builtin_amdgcn_s_setprio(1); \
    if (!isV) { \
        acc[0][0]=MF(a0,b0,acc[0][0]); acc[0][1]=MF(a0,b1,acc[0][1]); \
        acc[0][2]=MF(a0,b2,acc[0][2]); acc[0][3]=MF(a0,b3,acc[0][3]); \
        acc[1][0]=MF(a1,b0,acc[1][0]); acc[1][1]=MF(a1,b1,acc[1][1]); \
        acc[1][2]=MF(a1,b2,acc[1][2]); acc[1][3]=MF(a1,b3,acc[1][3]); \
        acc[2][0]=MF(a2,b0,acc[2][0]); acc[2][1]=MF(a2,b1,acc[2][1]); \
        acc[2][2]=MF(a2,b2,acc[2][2]); acc[2][3]=MF(a2,b3,acc[2][3]); \
        acc[3][0]=MF(a3,b0,acc[3][0]); acc[3][1]=MF(a3,b1,acc[3][1]); \
        acc[3][2]=MF(a3,b2,acc[3][2]); acc[3][3]=MF(a3,b3,acc[3][3]); \
    } else { \
        acc[0][0]=MF(b0,a0,acc[0][0]); acc[0][1]=MF(b1,a0,acc[0][1]); \
        acc[0][2]=MF(b2,a0,acc[0][2]); acc[0][3]=MF(b3,a0,acc[0][3]); \
        acc[1][0]=MF(b0,a1,acc[1][0]); acc[1][1]=MF(b1,a1,acc[1][1]); \
        acc[1][2]=MF(b2,a1,acc[1][2]); acc[1][3]=MF(b3,a1,acc[1][3]); \
        acc[2][0]=MF(b0,a2,acc[2][0]); acc[2][1]=MF(b1,a2,acc[2][1]); \
        acc[2][2]=MF(b2,a2,acc[2][2]); acc[2][3]=MF(b3,a2,acc[2][3]); \
        acc[3][0]=MF(b0,a3,acc[3][0]); acc[3][1]=MF(b1,a3,acc[3][1]); \
        acc[3][2]=MF(b2,a3,acc[3][2]); acc[3][3]=MF(b3,a3,acc[3][3]); \
    } \
    __builtin_amdgcn_s_setprio(0); \
    VM0; \
    FENCE; __builtin_amdgcn_s_barrier(); FENCE; \
  } while (0)

__global__ __launch_bounds__(256)
void qkv_gemm_f16(const ushort* __restrict__ Ah, const ushort* __restrict__ Bh,
                  const float* __restrict__ bias,
                  ushort* __restrict__ qh, ushort* __restrict__ kh,
                  ushort* __restrict__ varr)
{
    __shared__ ushort lds[4 * 4096];   // 32 KB: A0,A1,B0,B1 chunks of 8 KB
    const int t = threadIdx.x;
    const int lane = t & 63, w = t >> 6;

    // XCD-aware bijective block swizzle (3072 blocks, 3072%8==0)
    const int id0 = blockIdx.y * 24 + blockIdx.x;
    const int ids = (id0 & 7) * 384 + (id0 >> 3);
    const int n0 = (ids % 24) * 128;
    const int m0 = (ids / 24) * 128;

    const int wm = (w >> 1) * 64;      // wave's M offset (2 waves in M)
    const int wn = (w & 1) * 64;       // wave's N offset (2 waves in N)
    const int fr = lane & 15;
    const int hq = lane >> 4;

    // staging: unit u -> row-pair rp=u>>3, phys slot u&7; source pre-swizzled:
    // logical slot8 = phys ^ (rp&7); row = rp*2 + (slot8>>2); col = (slot8&3)*8.
    const int u0 = t, u1 = 256 + t;
    const int rp0 = u0 >> 3, rp1 = u1 >> 3;
    const int sl0 = (u0 & 7) ^ (rp0 & 7), sl1 = (u1 & 7) ^ (rp1 & 7);
    const int r0 = rp0 * 2 + (sl0 >> 2), r1 = rp1 * 2 + (sl1 >> 2);
    const int c0 = (sl0 & 3) * 8,        c1 = (sl1 & 3) * 8;
    const ushort* aS0 = Ah + (size_t)(m0 + r0) * D_MODEL + c0;
    const ushort* aS1 = Ah + (size_t)(m0 + r1) * D_MODEL + c1;
    const ushort* bS0 = Bh + (size_t)(n0 + r0) * D_MODEL + c0;
    const ushort* bS1 = Bh + (size_t)(n0 + r1) * D_MODEL + c1;
    const int d0 = w * 512;            // wave-uniform LDS slice, load 0
    const int d1 = 2048 + w * 512;     // load 1

    // fragment-read offset (lane-constant): row = base + fr, k-slot = hq
    const int rdo  = ((fr >> 1) * 64) + ((((fr & 1) * 4 + hq) ^ ((fr >> 1) & 7)) * 8);
    const AS3U* lA = (const AS3U*)lds + (wm * 32 + rdo);
    const AS3U* lB = (const AS3U*)lds + (8192 + wn * 32 + rdo);

    const int cgb = n0 + wn;                    // 64-aligned output-column base
    const int typ = __builtin_amdgcn_readfirstlane((cgb % 192) / 64); // 0=q,1=k,2=v
    const bool isV = (typ == 2);

    f32x4 acc[4][4] = {};   // q/k: acc[i][j] = D[s i][ci j]; v: transposed

    // ---- prologue ----
    STAGE_AB(0, 0);
    VM0;
    __builtin_amdgcn_s_barrier();
    FENCE;

    // ---- main loop: 32 K-steps, double-buffered, 1 barrier/step ----
    #pragma unroll 1
    for (int it = 0; it < 15; ++it) {
        STEP(0, STAGE_AB(1, 2*it + 1));
        STEP(1, STAGE_AB(0, 2*it + 2));
    }
    STEP(0, STAGE_AB(1, 31));
    STEP(1, );

    // ---- epilogue: C/D row=(lane>>4)*4+r, col=lane&15 (validated r0-r4) ----
    const int col = lane & 15, rq = (lane >> 4) * 4;
    const int h   = cgb / 192;
    const int b   = m0 >> 12;
    const int sbl = (m0 & 4095) + wm;

    if (typ < 2) {
        ushort* dst = typ ? kh : qh;
        #pragma unroll
        for (int j = 0; j < 4; ++j) {
            const int ci = j*16 + col;
            const float bj = bias[cgb + ci];
            const size_t rowoff = ((size_t)(h*4 + b)*64 + ci) * SEQ;
            #pragma unroll
            for (int i = 0; i < 4; ++i) {
                const int s0 = sbl + i*16 + rq;            // multiple of 4
                float v0 = acc[i][j][0] + bj, v1 = acc[i][j][1] + bj;
                float v2 = acc[i][j][2] + bj, v3 = acc[i][j][3] + bj;
                if (s0 < 32) {
                    // RoPE: angle = ci * 10000^(-mp/16) = ci*exp(-mp*ln1e4/16)
                    int mp = s0 >> 1;
                    float if0 = __expf(-0.5756462732485115f * (float)mp);
                    float if1 = __expf(-0.5756462732485115f * (float)(mp + 1));
                    float a0 = (float)ci * if0, a1 = (float)ci * if1;
                    float cc0 = __cosf(a0), s0n = __sinf(a0);
                    float cc1 = __cosf(a1), s1n = __sinf(a1);
                    float n0_ = v0*cc0 - v1*s0n, n1_ = v1*cc0 + v0*s0n;
                    float n2_ = v2*cc1 - v3*s1n, n3_ = v3*cc1 + v2*s1n;
                    v0 = n0_; v1 = n1_; v2 = n2_; v3 = n3_;
                }
                *(ushort4*)&dst[rowoff + s0] = make_ushort4(
                    f2h(v0), f2h(v1), f2h(v2), f2h(v3));
            }
        }
    } else {
        // swapped-operand acc: acc[i][j][r] is at ci = j*16+rq+r, s = sbl+i*16+col
        const size_t base = (size_t)(h*4 + b) * SEQ;
        #pragma unroll
        for (int j = 0; j < 4; ++j) {
            const float4 b4 = *(const float4*)&bias[cgb + j*16 + rq];
            #pragma unroll
            for (int i = 0; i < 4; ++i) {
                const int s = sbl + i*16 + col;
                *(ushort4*)&varr[(base + s)*64 + j*16 + rq] = make_ushort4(
                    f2h(acc[i][j][0] + b4.x), f2h(acc[i][j][1] + b4.y),
                    f2h(acc[i][j][2] + b4.z), f2h(acc[i][j][3] + b4.w));
            }
        }
    }
}

// ---------------- K2: partial scores (MFMA) per K-chunk ----------------
__global__ __launch_bounds__(256)
void scores_partial(const ushort* __restrict__ qh, const ushort* __restrict__ kh,
                    float* __restrict__ partial)
{
    __shared__ float L[4 * 4096];   // 64 KB: per-wave 64x64 partials
    const int t = threadIdx.x, lane = t & 63, w = t >> 6;
    const int hb = blockIdx.x, chunk = blockIdx.y;
    const ushort* qb = qh + (size_t)hb * 64 * SEQ;
    const ushort* kb = kh + (size_t)hb * 64 * SEQ;
    const int fr = lane & 15, fq = (lane >> 4) * 8;

    f32x4 acc[4][4] = {};
    const int kbase = chunk * CH_S + w * (CH_S / 4);
    for (int kk = 0; kk < CH_S / 4; kk += 32) {
        const int k0 = kbase + kk;
        f16x8 af[4], bf[4];
        #pragma unroll
        for (int i = 0; i < 4; ++i)
            af[i] = *(const f16x8*)&qb[(size_t)(i*16 + fr) * SEQ + k0 + fq];
        #pragma unroll
        for (int j = 0; j < 4; ++j)
            bf[j] = *(const f16x8*)&kb[(size_t)(j*16 + fr) * SEQ + k0 + fq];
        #pragma unroll
        for (int i = 0; i < 4; ++i)
            #pragma unroll
            for (int j = 0; j < 4; ++j)
                acc[i][j] = __builtin_amdgcn_mfma_f32_16x16x32_f16(
                                af[i], bf[j], acc[i][j], 0, 0, 0);
    }

    float* Lw = &L[w * 4096];
    const int col = lane & 15, rq = (lane >> 4) * 4;
    #pragma unroll
    for (int i = 0; i < 4; ++i)
        #pragma unroll
        for (int j = 0; j < 4; ++j)
            #pragma unroll
            for (int r = 0; r < 4; ++r)
                Lw[(i*16 + rq + r)*64 + j*16 + col] = acc[i][j][r];
    __syncthreads();

    float* pb = partial + ((size_t)hb * NCHUNK + chunk) * 4096;
    #pragma unroll
    for (int u = 0; u < 4; ++u) {
        int idx = u*1024 + t*4;
        f32x4 s = *(f32x4*)&L[idx];
        s += *(f32x4*)&L[4096 + idx];
        s += *(f32x4*)&L[8192 + idx];
        s += *(f32x4*)&L[12288 + idx];
        *(f32x4*)&pb[idx] = s;
    }
}

// ---------------- K3: sum chunks, softmax over e; P fp16 [d][e] ----------------
__global__ __launch_bounds__(256)
void softmax_k(const float* __restrict__ partial, ushort* __restrict__ Pt)
{
    __shared__ float L[64 * 65];   // padded: row d at L[d*65]
    const int t = threadIdx.x;
    const int hb = blockIdx.x;
    const float* pb = partial + (size_t)hb * NCHUNK * 4096;

    #pragma unroll
    for (int u = 0; u < 16; ++u) {
        int idx = u*256 + t;              // coalesced global reads
        float s = 0.f;
        #pragma unroll
        for (int c = 0; c < NCHUNK; ++c) s += pb[c*4096 + idx];
        L[(idx >> 6) * 65 + (idx & 63)] = s;
    }
    __syncthreads();

    if (t < 64) {
        float* row = &L[t * 65];          // stride 65: conflict-free across lanes
        float mx = -1e30f;
        for (int e = 0; e < 64; ++e) mx = fmaxf(mx, row[e]);
        float sum = 0.f;
        for (int e = 0; e < 64; ++e) {
            float v = expf(0.125f * (row[e] - mx));
            row[e] = v; sum += v;
        }
        float inv = 1.f / sum;
        ushort* pd = Pt + (size_t)hb * 4096 + t * 64;
        for (int e = 0; e < 64; ++e) pd[e] = f2h(row[e] * inv);
    }
}

// ---------------- K4: out^T[s][d] = sum_e v[s][e] * P[d][e]  (MFMA, K=64) ----------------
__global__ __launch_bounds__(256)
void attn_out_mfma(const ushort* __restrict__ varr, const ushort* __restrict__ Pt,
                   float* __restrict__ out)
{
    const int t = threadIdx.x, lane = t & 63, w = t >> 6;
    const int hb = blockIdx.x;
    const int sb = blockIdx.y * 256 + w * 64;
    const int fr = lane & 15, fq = (lane >> 4) * 8;

    const ushort* Pb = Pt + (size_t)hb * 4096;
    const ushort* vb = varr + (size_t)hb * SEQ * 64;

    f16x8 aV[4][2], bP[4][2];
    #pragma unroll
    for (int i = 0; i < 4; ++i)
        #pragma unroll
        for (int ks = 0; ks < 2; ++ks)
            aV[i][ks] = *(const f16x8*)&vb[(size_t)(sb + i*16 + fr)*64 + ks*32 + fq];
    #pragma unroll
    for (int j = 0; j < 4; ++j)
        #pragma unroll
        for (int ks = 0; ks < 2; ++ks)
            bP[j][ks] = *(const f16x8*)&Pb[(j*16 + fr)*64 + ks*32 + fq];

    f32x4 acc[4][4] = {};   // [s-tile][d-tile]
    #pragma unroll
    for (int ks = 0; ks < 2; ++ks)
        #pragma unroll
        for (int i = 0; i < 4; ++i)
            #pragma unroll
            for (int j = 0; j < 4; ++j)
                acc[i][j] = __builtin_amdgcn_mfma_f32_16x16x32_f16(
                                aV[i][ks], bP[j][ks], acc[i][j], 0, 0, 0);

    const int col = lane & 15, rq = (lane >> 4) * 4;
    const int h = hb >> 2, b = hb & 3;
    #pragma unroll
    for (int i = 0; i < 4; ++i)
        #pragma unroll
        for (int j = 0; j < 4; ++j) {
            const int dg = j*16 + col;
            size_t off = (((size_t)h*64 + dg)*4 + b)*SEQ + sb + i*16 + rq;
            *(float4*)&out[off] = make_float4(acc[i][j][0], acc[i][j][1],
                                              acc[i][j][2], acc[i][j][3]);
        }
}

// ---------------- launcher ----------------
extern "C" void kernel_launch(void* const* d_in, const int* in_sizes, int n_in,
                              void* d_out, int out_size, void* d_ws, size_t ws_size,
                              hipStream_t stream)
{
    const float* x    = (const float*)d_in[0];
    const float* W    = (const float*)d_in[1];
    const float* bias = (const float*)d_in[2];
    float* out = (float*)d_out;

    char* p = (char*)d_ws;
    ushort* qh   = (ushort*)p;  p += (size_t)HB * 64 * SEQ * 2;        // 33.6 MB
    ushort* kh   = (ushort*)p;  p += (size_t)HB * 64 * SEQ * 2;        // 33.6 MB
    ushort* varr = (ushort*)p;  p += (size_t)HB * SEQ * 64 * 2;        // 33.6 MB
    ushort* Pth  = (ushort*)p;  p += (size_t)HB * 4096 * 2;            //  0.5 MB
    float* partial = (float*)p; p += (size_t)HB * NCHUNK * 4096 * 4;   //  8.4 MB
    ushort* xh   = (ushort*)p;  p += (size_t)BS * D_MODEL * 2;         // 33.6 MB
    ushort* Wh   = (ushort*)p;  p += (size_t)QKV_N * D_MODEL * 2;      //  6.3 MB

    const int nx = BS * D_MODEL;       // 16777216
    const int nw = QKV_N * D_MODEL;    // 3145728
    cvt_both<<<(nx + nw)/2048, 256, 0, stream>>>(x, W, xh, Wh, nx);

    qkv_gemm_f16<<<dim3(QKV_N/128, BS/128), 256, 0, stream>>>(
        xh, Wh, bias, qh, kh, varr);

    scores_partial<<<dim3(HB, NCHUNK), 256, 0, stream>>>(qh, kh, partial);
    softmax_k<<<HB, 256, 0, stream>>>(partial, Pth);
    attn_out_mfma<<<dim3(HB, 16), 256, 0, stream>>>(varr, Pth, out);
}